// Round 10
// baseline (11.314 us; speedup 1.0000x reference)
//
#include <hip/hip_runtime.h>

typedef float f4 __attribute__((ext_vector_type(4)));

#define TOTAL_F4   (8192 * 196)   // output f4s == input f4s
#define BLK_THR    448            // 7 waves per block
#define UNITS      2              // consecutive 448-f4 superblocks per block
#define NBLOCKS    (TOTAL_F4 / (BLK_THR * UNITS))   // 1792, exact

// Analytic solution of the 4-qubit circuit (Heisenberg picture):
//   z0 = cos(p0) cos(t0)
//   z1 = cos(p0) cos(t0) cos(t1+p1)
//   z2 = z1 * [cos(p4) cos(t2) + sin(p4) sin(p2) sin(t2) sin(t3+p3)]
//   z3 = cos(t2) cos(t3+p3)
// (t0,t1,t2,t3) = (TL, TR, BL, BR) pixels of the 2x2 patch. Exact.
//
// Block-level layout trick (R8, kept): 448 consecutive input f4s = 1792
// floats = 64 whole image rows = 32 row-pairs containing exactly 448
// patches whose output f4 indices are the SAME 448 consecutive slots.
// This round: 2 consecutive superblocks per block -> half the blocks/waves,
// 2x loads in flight per thread, identical lane-contiguity and stream
// locality in both directions.
__global__ __launch_bounds__(BLK_THR) void quanv_kernel(
    const float* __restrict__ x,   // [B*784]
    const float* __restrict__ rp,  // [5]
    f4* __restrict__ out)          // [B*196] f4
{
    __shared__ float lds[BLK_THR * 4 * UNITS];   // 14336 B
    int t = threadIdx.x;
    size_t gbase = (size_t)blockIdx.x * (BLK_THR * UNITS);

    // stage both superblocks: perfectly contiguous 16B/lane, 2 loads in flight
    ((f4*)lds)[t]           = ((const f4*)x)[gbase + t];
    ((f4*)lds)[t + BLK_THR] = ((const f4*)x)[gbase + t + BLK_THR];
    __syncthreads();

    // thread -> (local row-pair q, patch col pj)
    int q  = t / 14;
    int pj = t - q * 14;
    int o  = 56 * q + 2 * pj;       // float offset of TL pixel in superblock 0

    // uniform circuit constants
    float p1 = rp[1], p3 = rp[3];
    float K0  = __cosf(rp[0]);
    float K4  = __cosf(rp[4]);
    float K24 = __sinf(rp[4]) * __sinf(rp[2]);

    #define DO_UNIT(OFF_F, OFF_O) {                          \
        float t0 = lds[(OFF_F) + o],      t1 = lds[(OFF_F) + o + 1];  \
        float t2 = lds[(OFF_F) + o + 28], t3 = lds[(OFF_F) + o + 29]; \
        float ct0 = __cosf(t0);                              \
        float c1  = __cosf(t1 + p1);                         \
        float st2, ct2; __sincosf(t2, &st2, &ct2);           \
        float s3, c3;   __sincosf(t3 + p3, &s3, &c3);        \
        float z0 = K0 * ct0;                                 \
        float z1 = z0 * c1;                                  \
        float z2 = z1 * (K4 * ct2 + K24 * st2 * s3);         \
        float z3 = ct2 * c3;                                 \
        __builtin_nontemporal_store((f4){z0, z1, z2, z3},    \
                                    out + gbase + (OFF_O) + t); }

    DO_UNIT(0, 0)
    DO_UNIT(BLK_THR * 4, BLK_THR)
    #undef DO_UNIT
}

extern "C" void kernel_launch(void* const* d_in, const int* in_sizes, int n_in,
                              void* d_out, int out_size, void* d_ws, size_t ws_size,
                              hipStream_t stream) {
    const float* x  = (const float*)d_in[0];
    const float* rp = (const float*)d_in[1];
    f4* out = (f4*)d_out;
    quanv_kernel<<<NBLOCKS, BLK_THR, 0, stream>>>(x, rp, out);
}

// Round 11
// 10.882 us; speedup vs baseline: 1.0397x; 1.0397x over previous
//
#include <hip/hip_runtime.h>

typedef float f4 __attribute__((ext_vector_type(4)));

#define TOTAL_F4   (8192 * 196)   // output f4s == input f4s (both 25.7MB)
#define BLK_THR    448            // 7 waves per block
#define NBLOCKS    (TOTAL_F4 / BLK_THR)   // 3584, exact

// Analytic solution of the 4-qubit circuit (Heisenberg picture):
//   z0 = cos(p0) cos(t0)
//   z1 = cos(p0) cos(t0) cos(t1+p1)
//   z2 = z1 * [cos(p4) cos(t2) + sin(p4) sin(p2) sin(t2) sin(t3+p3)]
//   z3 = cos(t2) cos(t3+p3)
// (t0,t1,t2,t3) = (TL, TR, BL, BR) pixels of the 2x2 patch. Exact.
//
// Block-level layout trick: 448 consecutive input f4s = 1792 floats =
// 64 whole image rows = 32 row-pairs (rows never straddle: 784%28==0,
// 1792%28==0). Those 32 row-pairs contain exactly 448 patches, and their
// output f4 indices are the SAME 448 consecutive slots:
//   out_idx = q_global*14 + pj = 448*blk + (14*q_local + pj) = 448*blk + tid.
// So: stage 7168B contiguous -> LDS, compute 1 patch/thread from 4 floats,
// store 7168B contiguous. Both global streams are perfectly coalesced and
// 64B-line-exact. Measured 11.07us = 4.64 TB/s effective (74% of the
// 6.3 TB/s copy ceiling) — BW-bound floor for this 51.4MB mixed stream.
__global__ __launch_bounds__(BLK_THR) void quanv_kernel(
    const float* __restrict__ x,   // [B*784]
    const float* __restrict__ rp,  // [5]
    f4* __restrict__ out)          // [B*196] f4
{
    __shared__ float lds[BLK_THR * 4];   // 7168 B
    int t = threadIdx.x;
    size_t gbase = (size_t)blockIdx.x * BLK_THR;

    // stage: perfectly contiguous 16B/lane
    ((f4*)lds)[t] = ((const f4*)x)[gbase + t];
    __syncthreads();

    // thread -> (local row-pair q, patch col pj)
    int q  = t / 14;
    int pj = t - q * 14;
    int o  = 56 * q + 2 * pj;       // float offset of TL pixel in LDS
    float t0 = lds[o],      t1 = lds[o + 1];
    float t2 = lds[o + 28], t3 = lds[o + 29];

    // uniform circuit constants
    float p1 = rp[1], p3 = rp[3];
    float K0  = __cosf(rp[0]);
    float K4  = __cosf(rp[4]);
    float K24 = __sinf(rp[4]) * __sinf(rp[2]);

    float ct0 = __cosf(t0);
    float c1  = __cosf(t1 + p1);
    float st2, ct2; __sincosf(t2, &st2, &ct2);
    float s3, c3;   __sincosf(t3 + p3, &s3, &c3);
    float z0 = K0 * ct0;
    float z1 = z0 * c1;
    float z2 = z1 * (K4 * ct2 + K24 * st2 * s3);
    float z3 = ct2 * c3;

    __builtin_nontemporal_store((f4){z0, z1, z2, z3}, out + gbase + t);
}

extern "C" void kernel_launch(void* const* d_in, const int* in_sizes, int n_in,
                              void* d_out, int out_size, void* d_ws, size_t ws_size,
                              hipStream_t stream) {
    const float* x  = (const float*)d_in[0];
    const float* rp = (const float*)d_in[1];
    f4* out = (f4*)d_out;
    quanv_kernel<<<NBLOCKS, BLK_THR, 0, stream>>>(x, rp, out);
}